// Round 1
// baseline (64501.733 us; speedup 1.0000x reference)
//
#include <hip/hip_runtime.h>
#include <hip/hip_bf16.h>

typedef __attribute__((ext_vector_type(4))) float f32x4;
typedef __attribute__((ext_vector_type(8))) short short8;
typedef unsigned short u16;

constexpr int B = 64, S = 512, KIN = 512, H = 1024;

// ---- workspace layout (bytes) ----
constexpr size_t OFF_CNT   = 0;
constexpr size_t OFF_H0BF  = 1024;
constexpr size_t SZ_HBF    = (size_t)2*2*B*H*2;   // [dir][slot][B][H] bf16
constexpr size_t OFF_H1BF  = OFF_H0BF + SZ_HBF;
constexpr size_t SZ_HF32   = (size_t)2*2*B*H*4;
constexpr size_t OFF_H0F32 = OFF_H1BF + SZ_HBF;
constexpr size_t OFF_H1F32 = OFF_H0F32 + SZ_HF32;
constexpr size_t OFF_ZEND  = OFF_H1F32 + SZ_HF32;        // zeroed region end
constexpr size_t OFF_XBF   = (OFF_ZEND + 255) & ~(size_t)255;
constexpr size_t SZ_XBF    = (size_t)S*B*KIN*2;          // [t][b][k] bf16
constexpr size_t OFF_WP    = OFF_XBF + SZ_XBF;
constexpr size_t WP_ELEMS0 = (size_t)64*48*1536;         // per layer-0 cell
constexpr size_t WP_ELEMS1 = (size_t)64*48*2048;         // per layer-1 cell

__device__ __forceinline__ u16 f2bf(float v) {
    __hip_bfloat16 h = __float2bfloat16(v);
    return *reinterpret_cast<u16*>(&h);
}

// Pack weights to bf16, per-block-contiguous [cell][blk][c(48)][K], c: 0-15=r,16-31=z,32-47=n.
// Cell 1 (layer0 backward): fold the feature reversal by reversing w_ih's K axis.
__global__ void pack_w(const float* __restrict__ wi0f, const float* __restrict__ wh0f,
                       const float* __restrict__ wi0b, const float* __restrict__ wh0b,
                       const float* __restrict__ wi1f, const float* __restrict__ wh1f,
                       const float* __restrict__ wi1b, const float* __restrict__ wh1b,
                       u16* __restrict__ wp) {
    int bx = blockIdx.x;
    int cell = bx / (64*48);
    int rem  = bx % (64*48);
    int blk = rem / 48, c = rem % 48;
    int K  = (cell < 2) ? 1536 : 2048;
    int Ki = (cell < 2) ? 512  : 1024;
    int n = (c >> 4)*H + blk*16 + (c & 15);
    const float* wi = (cell==0)?wi0f:(cell==1)?wi0b:(cell==2)?wi1f:wi1b;
    const float* wh = (cell==0)?wh0f:(cell==1)?wh0b:(cell==2)?wh1f:wh1b;
    size_t base = (cell==0)?0:(cell==1)?WP_ELEMS0:(cell==2)?2*WP_ELEMS0:2*WP_ELEMS0+WP_ELEMS1;
    u16* dst = wp + base + ((size_t)blk*48 + c)*K;
    for (int k = threadIdx.x; k < K; k += 256) {
        float v;
        if (k < Ki) v = wi[(size_t)n*Ki + ((cell==1) ? (Ki-1-k) : k)];
        else        v = wh[(size_t)n*H + (k - Ki)];
        dst[k] = f2bf(v);
    }
}

// x (B,S,IN) fp32 -> xbf [t][b][k] bf16
__global__ void conv_x(const float* __restrict__ x, u16* __restrict__ xbf) {
    int t = blockIdx.x >> 6;
    int b = blockIdx.x & 63;
    const float* src = x + ((size_t)b*S + t)*KIN;
    u16* dst = xbf + ((size_t)t*B + b)*KIN;
    for (int k = threadIdx.x; k < KIN; k += 256)
        dst[k] = f2bf(src[k]);
}

struct PArgs {
    const u16* wp;
    const u16* xbf;
    const float* bih0f; const float* bhh0f;
    const float* bih0b; const float* bhh0b;
    const float* bih1f; const float* bhh1f;
    const float* bih1b; const float* bhh1b;
    u16* h0bf; u16* h1bf;
    float* h0f32; float* h1f32;
    float* out;    // [B][S][2H]
    float* out2;   // [B][2H]
    unsigned* cnt;
};

// 256 blocks x 256 threads, persistent. block = (cell<<6)|blk; cell 0=0f,1=0b,2=1f,3=1b.
// Tick tau: layer0 computes t=tau (tau<S); layer1 computes t=tau-1 (tau>=1). One barrier/tick.
__launch_bounds__(256)
__global__ void gru_persist(PArgs a) {
    __shared__ u16 smA[64*256];   // A chunk, XOR-swizzled rows of 256 bf16
    __shared__ u16 smW[48*256];   // W chunk

    const int tid  = threadIdx.x;
    const int lane = tid & 63;
    const int wave = tid >> 6;
    const int cell = blockIdx.x >> 6;
    const int blk  = blockIdx.x & 63;
    const int j0   = blk * 16;
    const int cix  = lane & 15;
    const int q    = lane >> 4;
    const int jl   = j0 + cix;
    const int K    = (cell < 2) ? 1536 : 2048;
    const int nch  = K >> 8;                 // 256-wide K chunks
    const int nich = (cell < 2) ? 2 : 4;     // chunks belonging to the gi (input) part
    const int dir  = cell & 1;

    const float* bih = (cell==0)?a.bih0f:(cell==1)?a.bih0b:(cell==2)?a.bih1f:a.bih1b;
    const float* bhh = (cell==0)?a.bhh0f:(cell==1)?a.bhh0b:(cell==2)?a.bhh1f:a.bhh1b;
    const float br   = bih[jl]       + bhh[jl];
    const float bz   = bih[H + jl]   + bhh[H + jl];
    const float bi_n = bih[2*H + jl];
    const float bh_n = bhh[2*H + jl];

    size_t wbase = (cell==0)?0:(cell==1)?WP_ELEMS0:(cell==2)?2*WP_ELEMS0:2*WP_ELEMS0+WP_ELEMS1;
    const u16* wblk = a.wp + wbase + (size_t)blk*48*K;

    u16*  myh0b = a.h0bf  + (size_t)dir*2*B*H;
    u16*  myh1b = a.h1bf  + (size_t)dir*2*B*H;
    float* myh0f = a.h0f32 + (size_t)dir*2*B*H;
    float* myh1f = a.h1f32 + (size_t)dir*2*B*H;

    unsigned target = 0;
    for (int tick = 0; tick <= S; ++tick) {
        const bool active = (cell < 2) ? (tick < S) : (tick >= 1);
        const int t = (cell < 2) ? tick : (tick - 1);
        if (active) {
            const int sprev = (t + 1) & 1, scur = t & 1;
            f32x4 ar = {0,0,0,0}, az = {0,0,0,0}, ani = {0,0,0,0}, anh = {0,0,0,0};
            for (int ct = 0; ct < nch; ++ct) {
                const u16* asrc; int aLd;
                if (cell < 2) {
                    if (ct < 2) { asrc = a.xbf + (size_t)t*B*KIN + ct*256;          aLd = KIN; }
                    else        { asrc = myh0b + (size_t)sprev*B*H + (ct-2)*256;    aLd = H; }
                } else {
                    if (ct < 4) { asrc = myh0b + (size_t)scur*B*H + ct*256;         aLd = H; }
                    else        { asrc = myh1b + (size_t)sprev*B*H + (ct-4)*256;    aLd = H; }
                }
                // stage A: 64 rows x 32 16B-chunks, swizzle chunk^(row&15)
                for (int i = tid; i < 2048; i += 256) {
                    int row = i >> 5, ch = i & 31;
                    uint4 v = *(const uint4*)(asrc + (size_t)row*aLd + ch*8);
                    ((uint4*)smA)[row*32 + (ch ^ (row & 15))] = v;
                }
                // stage W: 48 rows x 32 chunks
                const u16* wsrc = wblk + ct*256;
                for (int i = tid; i < 1536; i += 256) {
                    int row = i >> 5, ch = i & 31;
                    uint4 v = *(const uint4*)(wsrc + (size_t)row*K + ch*8);
                    ((uint4*)smW)[row*32 + (ch ^ (row & 15))] = v;
                }
                __syncthreads();
                const bool isI = (ct < nich);
                const int arow = wave*16 + cix;
                #pragma unroll
                for (int ks = 0; ks < 8; ++ks) {
                    int sw = (ks*4 + q) ^ cix;
                    uint4 av = ((const uint4*)smA)[arow*32 + sw];
                    uint4 w0 = ((const uint4*)smW)[cix*32 + sw];
                    uint4 w1 = ((const uint4*)smW)[(16 + cix)*32 + sw];
                    uint4 w2 = ((const uint4*)smW)[(32 + cix)*32 + sw];
                    short8 af = __builtin_bit_cast(short8, av);
                    ar = __builtin_amdgcn_mfma_f32_16x16x32_bf16(af, __builtin_bit_cast(short8, w0), ar, 0,0,0);
                    az = __builtin_amdgcn_mfma_f32_16x16x32_bf16(af, __builtin_bit_cast(short8, w1), az, 0,0,0);
                    if (isI) ani = __builtin_amdgcn_mfma_f32_16x16x32_bf16(af, __builtin_bit_cast(short8, w2), ani, 0,0,0);
                    else     anh = __builtin_amdgcn_mfma_f32_16x16x32_bf16(af, __builtin_bit_cast(short8, w2), anh, 0,0,0);
                }
                __syncthreads();
            }
            // elementwise GRU update. C/D layout: col=lane&15 (n idx), row=q*4+v (m idx)
            float* hprevf = ((cell < 2) ? myh0f : myh1f) + (size_t)sprev*B*H;
            float* hcurf  = ((cell < 2) ? myh0f : myh1f) + (size_t)scur*B*H;
            u16*   hcurb  = ((cell < 2) ? myh0b : myh1b) + (size_t)scur*B*H;
            #pragma unroll
            for (int v = 0; v < 4; ++v) {
                int brow = wave*16 + q*4 + v;
                float r = 1.f/(1.f + __expf(-(ar[v] + br)));
                float z = 1.f/(1.f + __expf(-(az[v] + bz)));
                float xn = (ani[v] + bi_n) + r*(anh[v] + bh_n);
                float e2 = __expf(2.f*xn);
                float n = 1.f - 2.f/(e2 + 1.f);         // tanh, no inf/inf
                float hp = hprevf[(size_t)brow*H + jl];
                float hn = (1.f - z)*n + z*hp;
                hcurf[(size_t)brow*H + jl] = hn;
                hcurb[(size_t)brow*H + jl] = f2bf(hn);
                if (cell >= 2) {
                    a.out[((size_t)brow*S + t)*(2*H) + dir*H + jl] = hn;
                    if (t == S-1) a.out2[(size_t)brow*(2*H) + dir*H + jl] = hn;
                }
            }
        }
        // grid barrier (all 256 blocks arrive every tick)
        target += 256;
        if (tick < S) {
            __threadfence();
            __syncthreads();
            if (tid == 0) {
                __hip_atomic_fetch_add(a.cnt, 1u, __ATOMIC_ACQ_REL, __HIP_MEMORY_SCOPE_AGENT);
                while (__hip_atomic_load(a.cnt, __ATOMIC_ACQUIRE, __HIP_MEMORY_SCOPE_AGENT) < target) {
                    __builtin_amdgcn_s_sleep(1);
                }
            }
            __syncthreads();
            __threadfence();
        }
    }
}

extern "C" void kernel_launch(void* const* d_in, const int* in_sizes, int n_in,
                              void* d_out, int out_size, void* d_ws, size_t ws_size,
                              hipStream_t stream) {
    const float* x    = (const float*)d_in[0];
    const float* wi0f = (const float*)d_in[1];
    const float* wh0f = (const float*)d_in[2];
    const float* bi0f = (const float*)d_in[3];
    const float* bh0f = (const float*)d_in[4];
    const float* wi0b = (const float*)d_in[5];
    const float* wh0b = (const float*)d_in[6];
    const float* bi0b = (const float*)d_in[7];
    const float* bh0b = (const float*)d_in[8];
    const float* wi1f = (const float*)d_in[9];
    const float* wh1f = (const float*)d_in[10];
    const float* bi1f = (const float*)d_in[11];
    const float* bh1f = (const float*)d_in[12];
    const float* wi1b = (const float*)d_in[13];
    const float* wh1b = (const float*)d_in[14];
    const float* bi1b = (const float*)d_in[15];
    const float* bh1b = (const float*)d_in[16];

    char* ws = (char*)d_ws;
    hipMemsetAsync(ws, 0, OFF_ZEND, stream);   // barrier counter + h states = 0

    u16* xbf = (u16*)(ws + OFF_XBF);
    u16* wp  = (u16*)(ws + OFF_WP);

    pack_w<<<4*64*48, 256, 0, stream>>>(wi0f, wh0f, wi0b, wh0b, wi1f, wh1f, wi1b, wh1b, wp);
    conv_x<<<S*B, 256, 0, stream>>>(x, xbf);

    PArgs a;
    a.wp = wp; a.xbf = xbf;
    a.bih0f = bi0f; a.bhh0f = bh0f; a.bih0b = bi0b; a.bhh0b = bh0b;
    a.bih1f = bi1f; a.bhh1f = bh1f; a.bih1b = bi1b; a.bhh1b = bh1b;
    a.h0bf = (u16*)(ws + OFF_H0BF); a.h1bf = (u16*)(ws + OFF_H1BF);
    a.h0f32 = (float*)(ws + OFF_H0F32); a.h1f32 = (float*)(ws + OFF_H1F32);
    a.out  = (float*)d_out;
    a.out2 = (float*)d_out + (size_t)B*S*2*H;
    a.cnt  = (unsigned*)(ws + OFF_CNT);
    gru_persist<<<256, 256, 0, stream>>>(a);
}